// Round 14
// baseline (107.828 us; speedup 1.0000x reference)
//
#include <hip/hip_runtime.h>

#define NROWS 8192
#define HALF_N 4096
#define DIM 512
#define INV_T 10.0f
#define NRB 64              // number of 128-row blocks
#define NBLOCKS 2080        // 64*65/2 upper-triangle block pairs

typedef __attribute__((ext_vector_type(4))) float f32x4;
typedef __attribute__((ext_vector_type(2))) long long2v;

// Kernel 1: L2-normalize rows of [f1;f2] -> fp8 e4m3 in FRAGMENT-MAJOR
// layout Fa: panel p = row>>4 is 8 KB laid out [chunk c=0..31][row&15][16B];
// chunk c holds k-units {c&3, (c&3)+4} of k-group c>>2. A k-permutation
// shared by both GEMM operands leaves the dot products unchanged, and this
// one makes every fragment load a coalesced global b128.
__global__ __launch_bounds__(256) void norm_cast_k(
    const float* __restrict__ f1, const float* __restrict__ f2,
    unsigned char* __restrict__ Fa, float* __restrict__ rowsum,
    float* __restrict__ out) {
  int wave = threadIdx.x >> 6;
  int lane = threadIdx.x & 63;
  int row = blockIdx.x * 4 + wave;
  const float* src = (row < HALF_N) ? (f1 + (size_t)row * DIM)
                                    : (f2 + (size_t)(row - HALF_N) * DIM);
  const float4* p = reinterpret_cast<const float4*>(src + lane * 8);
  float4 v0 = p[0];
  float4 v1 = p[1];
  float ss = v0.x*v0.x + v0.y*v0.y + v0.z*v0.z + v0.w*v0.w
           + v1.x*v1.x + v1.y*v1.y + v1.z*v1.z + v1.w*v1.w;
  #pragma unroll
  for (int off = 1; off < 64; off <<= 1) ss += __shfl_xor(ss, off);
  float scale = 1.0f / fmaxf(sqrtf(ss), 1e-12f);
  int lo = __builtin_amdgcn_cvt_pk_fp8_f32(v0.x * scale, v0.y * scale, 0, false);
  lo = __builtin_amdgcn_cvt_pk_fp8_f32(v0.z * scale, v0.w * scale, lo, true);
  int hi = __builtin_amdgcn_cvt_pk_fp8_f32(v1.x * scale, v1.y * scale, 0, false);
  hi = __builtin_amdgcn_cvt_pk_fp8_f32(v1.z * scale, v1.w * scale, hi, true);
  int u = lane & 7;                     // k-unit within 64B group
  int g = lane >> 3;                    // k-group (0..7)
  int chunk = g * 4 + (u & 3);          // 16B chunk index (0..31)
  int slot = u >> 2;                    // 8B half within the chunk
  *reinterpret_cast<int2*>(Fa + (size_t)(row >> 4) * 8192 + chunk * 256 +
                           (row & 15) * 16 + slot * 8) = make_int2(lo, hi);
  if (lane == 0) rowsum[row] = 0.0f;
  if (blockIdx.x == 0 && threadIdx.x == 0) out[0] = 0.0f;
}

// Kernel 2: symmetric upper-triangle sim GEMM (fp8 e4m3), fused exp row/col
// accumulation. NO LDS OPERAND STAGING, NO K-LOOP BARRIERS: both A and B
// fragments load directly from the fragment-major Fa (coalesced b128,
// L2/LLC-resident 4 MB), manually double-buffered so each round's loads fly
// during the previous round's MFMAs (fine-grained vmcnt, never a full
// barrier drain — the thing the 2-barrier structure could not express).
__global__ __launch_bounds__(256, 3) void sym_gemm_k(
    const unsigned char* __restrict__ Fa, float* __restrict__ rowsum,
    float* __restrict__ pairsim) {
  // XCD-contiguous remap: each XCD (bx%8) gets a contiguous 260-block range
  int bx = blockIdx.x;
  int gbx = (bx & 7) * (NBLOCKS / 8) + (bx >> 3);
  int rb = 0, rem = gbx;
  while (rem >= NRB - rb) { rem -= NRB - rb; ++rb; }
  const int cb = rb + rem;
  const int row0 = rb * 128, col0 = cb * 128;

  const int tid = threadIdx.x;
  const int wave = tid >> 6;
  const int lane = tid & 63;
  const int quad = lane >> 4;
  const int colid = lane & 15;
  const int wr0 = (wave >> 1) * 64;   // wave's row offset within tile
  const int wc0 = (wave & 1) * 64;    // wave's col offset within tile

  __shared__ float redrow[128];
  __shared__ float redcol[128];
  if (tid < 128) { redrow[tid] = 0.0f; redcol[tid] = 0.0f; }
  __syncthreads();                     // init visible before epilogue atomics

  // Fragment pointers: tile t -> panel (base+t*16)>>4; round kc, quad q ->
  // chunk kc*4+q; colid -> row-in-panel. A quarter-wave reads 256 B
  // contiguous; a full wave 1 KB contiguous.
  const unsigned char* agp[4]; const unsigned char* bgp[4];
  #pragma unroll
  for (int t = 0; t < 4; ++t) {
    agp[t] = Fa + (size_t)((row0 + wr0 + t * 16) >> 4) * 8192 +
             quad * 256 + colid * 16;
    bgp[t] = Fa + (size_t)((col0 + wc0 + t * 16) >> 4) * 8192 +
             quad * 256 + colid * 16;
  }

  f32x4 acc[4][4];
  #pragma unroll
  for (int t = 0; t < 4; ++t)
    #pragma unroll
    for (int u = 0; u < 4; ++u) acc[t][u] = (f32x4){0.f, 0.f, 0.f, 0.f};

  // Depth-1 software pipeline over 8 K-rounds (BK=64 each).
  long2v af[2][4], bf[2][4];
  #pragma unroll
  for (int t = 0; t < 4; ++t) {
    af[0][t] = *reinterpret_cast<const long2v*>(agp[t]);
    bf[0][t] = *reinterpret_cast<const long2v*>(bgp[t]);
  }
  #pragma unroll
  for (int kc = 0; kc < 8; ++kc) {
    const int cur = kc & 1, nxt = cur ^ 1;
    if (kc < 7) {
      const int ko = (kc + 1) * 1024;  // next round's chunk block
      #pragma unroll
      for (int t = 0; t < 4; ++t) {
        af[nxt][t] = *reinterpret_cast<const long2v*>(agp[t] + ko);
        bf[nxt][t] = *reinterpret_cast<const long2v*>(bgp[t] + ko);
      }
    }
    #pragma unroll
    for (int s = 0; s < 2; ++s)
      #pragma unroll
      for (int t = 0; t < 4; ++t)
        #pragma unroll
        for (int u = 0; u < 4; ++u)
          acc[t][u] = __builtin_amdgcn_mfma_f32_16x16x32_fp8_fp8(
              af[cur][t][s], bf[cur][u][s], acc[t][u], 0, 0, 0);
  }

  // Epilogue. C/D layout: col = lane&15, row = quad*4 + reg (m89-verified,
  // dtype-independent on gfx950).
  float re[4][4];
  float ce[4];
  #pragma unroll
  for (int t = 0; t < 4; ++t)
    #pragma unroll
    for (int r = 0; r < 4; ++r) re[t][r] = 0.0f;
  #pragma unroll
  for (int u = 0; u < 4; ++u) ce[u] = 0.0f;

  #pragma unroll
  for (int t = 0; t < 4; ++t) {
    #pragma unroll
    for (int u = 0; u < 4; ++u) {
      f32x4 a = acc[t][u];
      const int gc = col0 + wc0 + u * 16 + colid;
      #pragma unroll
      for (int r = 0; r < 4; ++r) {
        int grow = row0 + wr0 + t * 16 + quad * 4 + r;
        float sim = a[r] * INV_T;
        float e = (gc > grow) ? __expf(sim) : 0.0f;  // strict upper triangle
        re[t][r] += e;
        ce[u] += e;
        if (gc == grow + HALF_N && grow < HALF_N) {
          pairsim[grow] = sim;         // unique writer per pair
          pairsim[gc] = sim;
        }
      }
    }
  }

  // Row sums: reduce across the 16 col-lanes, LDS-accumulate.
  #pragma unroll
  for (int t = 0; t < 4; ++t)
    #pragma unroll
    for (int r = 0; r < 4; ++r) {
      float v = re[t][r];
      v += __shfl_xor(v, 1); v += __shfl_xor(v, 2);
      v += __shfl_xor(v, 4); v += __shfl_xor(v, 8);
      if (colid == 0) atomicAdd(&redrow[wr0 + t * 16 + quad * 4 + r], v);
    }
  // Col sums: reduce across the 4 quads (this wave's 64 rows).
  #pragma unroll
  for (int u = 0; u < 4; ++u) {
    float v = ce[u];
    v += __shfl_xor(v, 16); v += __shfl_xor(v, 32);
    if (lane < 16) atomicAdd(&redcol[wc0 + u * 16 + colid], v);
  }
  __syncthreads();
  if (tid < 128) atomicAdd(&rowsum[row0 + tid], redrow[tid]);
  else           atomicAdd(&rowsum[col0 + tid - 128], redcol[tid - 128]);
}

// Kernel 3: loss partials. 32 blocks x 256 threads, one row each;
// per-wave reduce then one atomicAdd per wave into out (zeroed in kernel 1).
__global__ __launch_bounds__(256) void finalize_k(
    const float* __restrict__ rowsum, const float* __restrict__ pairsim,
    float* __restrict__ out) {
  int i = blockIdx.x * 256 + threadIdx.x;
  float local = logf(rowsum[i]) - pairsim[i];
  #pragma unroll
  for (int off = 1; off < 64; off <<= 1) local += __shfl_xor(local, off);
  if ((threadIdx.x & 63) == 0)
    atomicAdd(out, local * (1.0f / (float)NROWS));
}

extern "C" void kernel_launch(void* const* d_in, const int* in_sizes, int n_in,
                              void* d_out, int out_size, void* d_ws, size_t ws_size,
                              hipStream_t stream) {
  const float* f1 = (const float*)d_in[0];
  const float* f2 = (const float*)d_in[1];
  unsigned char* Fa = (unsigned char*)d_ws;                     // 4 MB fp8
  float* rowsum = (float*)(Fa + (size_t)NROWS * DIM);
  float* pairsim = rowsum + NROWS;
  float* out = (float*)d_out;

  norm_cast_k<<<NROWS / 4, 256, 0, stream>>>(f1, f2, Fa, rowsum, out);
  sym_gemm_k<<<NBLOCKS, 256, 0, stream>>>(Fa, rowsum, pairsim);
  finalize_k<<<NROWS / 256, 256, 0, stream>>>(rowsum, pairsim, out);
}

// Round 15
// 107.044 us; speedup vs baseline: 1.0073x; 1.0073x over previous
//
#include <hip/hip_runtime.h>

#define NROWS 8192
#define HALF_N 4096
#define DIM 512
#define NRB 64              // number of 128-row blocks
#define NBLOCKS 2080        // 64*65/2 upper-triangle block pairs
#define QS 423.3333333f     // 127 / 0.3  (quant scale)
#define SIMSCALE 5.5800111e-5f  // (0.3/127)^2 * 10  (dequant * 1/T)

typedef __attribute__((ext_vector_type(4))) float f32x4;
typedef __attribute__((ext_vector_type(4))) int i32x4;

// async 16B global -> LDS (DMA). LDS dest is wave-uniform base + lane*16.
__device__ __forceinline__ void async16(const void* g, void* l) {
  __builtin_amdgcn_global_load_lds(
      (const __attribute__((address_space(1))) unsigned int*)g,
      (__attribute__((address_space(3))) unsigned int*)l, 16, 0, 0);
}

__device__ __forceinline__ int pack4(float a, float b, float c, float d) {
  int q0 = __float2int_rn(a), q1 = __float2int_rn(b);
  int q2 = __float2int_rn(c), q3 = __float2int_rn(d);
  return (q0 & 255) | ((q1 & 255) << 8) | ((q2 & 255) << 16) | (q3 << 24);
}

// Kernel 1: L2-normalize rows of [f1;f2] -> int8 (global scale s=0.3),
// written twice:
//  Fb: row-major (natural k order) — the B/LDS-staging copy.
//  Fa: fragment-major — panel p=row>>4 is 8 KB: [chunk c=0..31][row&15][16B],
//      chunk c = k-bytes [16c,16c+16) — A-fragment loads become coalesced
//      global b128 (i8 K=64 fragment = 16 contiguous k-bytes, no permute).
__global__ __launch_bounds__(256) void norm_cast_k(
    const float* __restrict__ f1, const float* __restrict__ f2,
    unsigned char* __restrict__ Fa, unsigned char* __restrict__ Fb,
    float* __restrict__ rowsum, float* __restrict__ out) {
  int wave = threadIdx.x >> 6;
  int lane = threadIdx.x & 63;
  int row = blockIdx.x * 4 + wave;
  const float* src = (row < HALF_N) ? (f1 + (size_t)row * DIM)
                                    : (f2 + (size_t)(row - HALF_N) * DIM);
  const float4* p = reinterpret_cast<const float4*>(src + lane * 8);
  float4 v0 = p[0];
  float4 v1 = p[1];
  float ss = v0.x*v0.x + v0.y*v0.y + v0.z*v0.z + v0.w*v0.w
           + v1.x*v1.x + v1.y*v1.y + v1.z*v1.z + v1.w*v1.w;
  #pragma unroll
  for (int off = 1; off < 64; off <<= 1) ss += __shfl_xor(ss, off);
  float sc = QS / fmaxf(sqrtf(ss), 1e-12f);   // normalize + quant in one mul
  int lo = pack4(v0.x * sc, v0.y * sc, v0.z * sc, v0.w * sc);
  int hi = pack4(v1.x * sc, v1.y * sc, v1.z * sc, v1.w * sc);
  int2 val = make_int2(lo, hi);
  // Fb: row-major
  *reinterpret_cast<int2*>(Fb + (size_t)row * DIM + lane * 8) = val;
  // Fa: fragment-major; lane covers k-bytes [8*lane, 8*lane+8)
  int chunk = lane >> 1;                // 16B chunk index (0..31)
  int slot = lane & 1;                  // 8B half within the chunk
  *reinterpret_cast<int2*>(Fa + (size_t)(row >> 4) * 8192 + chunk * 256 +
                           (row & 15) * 16 + slot * 8) = val;
  if (lane == 0) rowsum[row] = 0.0f;
  if (blockIdx.x == 0 && threadIdx.x == 0) out[0] = 0.0f;
}

// Kernel 2: symmetric upper-triangle sim GEMM (i8, K=64 MFMA), fused exp
// row/col accumulation. R13 structure: 128x128 tiles, BK=64 (8 rounds);
// B staged via global_load_lds (8 x 1KB insts/round, proven ^((r>>1)&3)
// swizzle); A fragments direct from fragment-major Fa (coalesced b128,
// L2-resident). 16 MFMAs/round (half of the fp8 count, same bytes).
__global__ __launch_bounds__(256, 3) void sym_gemm_k(
    const unsigned char* __restrict__ Fa, const unsigned char* __restrict__ Fb,
    float* __restrict__ rowsum, float* __restrict__ pairsim) {
  // XCD-contiguous remap: each XCD (bx%8) gets a contiguous 260-block range
  int bx = blockIdx.x;
  int gbx = (bx & 7) * (NBLOCKS / 8) + (bx >> 3);
  int rb = 0, rem = gbx;
  while (rem >= NRB - rb) { rem -= NRB - rb; ++rb; }
  const int cb = rb + rem;
  const int row0 = rb * 128, col0 = cb * 128;

  const int tid = threadIdx.x;
  const int wave = tid >> 6;
  const int lane = tid & 63;
  const int quad = lane >> 4;
  const int colid = lane & 15;
  const int wr0 = (wave >> 1) * 64;   // wave's row offset within tile
  const int wc0 = (wave & 1) * 64;    // wave's col offset within tile

  // B LDS tile: 128 rows x 64 i8 = 64 B/row, 4 x 16B chunks per row.
  // Physical chunk = logical ^ ((row>>1)&3) -> conflict-free b128 reads.
  __shared__ __align__(16) unsigned char Blds[128 * 64];
  __shared__ float redrow[128];
  __shared__ float redcol[128];
  if (tid < 128) { redrow[tid] = 0.0f; redcol[tid] = 0.0f; }

  // B staging: 8 x 1KB insts/round, wave w owns insts {w, w+4}.
  // Inst i covers rows [i*16, i*16+16): lane -> r = i*16 + (lane>>2),
  // phys chunk = lane&3, global logical chunk = (lane&3) ^ ((r>>1)&3).
  const unsigned char* srcB[2]; unsigned char* dstB[2];
  #pragma unroll
  for (int seg = 0; seg < 2; ++seg) {
    int inst = wave + seg * 4;
    int r = inst * 16 + (lane >> 2);
    int c = (lane & 3) ^ ((r >> 1) & 3);
    srcB[seg] = Fb + (size_t)(col0 + r) * DIM + c * 16;
    dstB[seg] = Blds + inst * 1024;   // 16 rows x 64 B per inst
  }

  // A global fragment pointers: tile t -> panel (row0+wr0+t*16)>>4;
  // round kc, quad q -> chunk kc*4+q; colid -> row-in-panel.
  const unsigned char* agp[4];
  #pragma unroll
  for (int t = 0; t < 4; ++t)
    agp[t] = Fa + (size_t)((row0 + wr0 + t * 16) >> 4) * 8192 +
             quad * 256 + colid * 16;

  // B fragment LDS addresses: logical chunk = quad (k-bytes [16q,16q+16));
  // phys = quad ^ ((r>>1)&3).
  const unsigned char* bfp[4];
  #pragma unroll
  for (int t = 0; t < 4; ++t) {
    int rc = wc0 + t * 16 + colid;
    bfp[t] = Blds + rc * 64 + ((quad ^ ((rc >> 1) & 3)) << 4);
  }

  i32x4 acc[4][4];
  #pragma unroll
  for (int t = 0; t < 4; ++t)
    #pragma unroll
    for (int u = 0; u < 4; ++u) acc[t][u] = (i32x4){0, 0, 0, 0};

  for (int kc = 0; kc < 8; ++kc) {
    __syncthreads();                   // prior round's B reads done
    const size_t ko = (size_t)kc * 64; // B: 64 k-elems = 64 B per row
    #pragma unroll
    for (int seg = 0; seg < 2; ++seg)
      async16(srcB[seg] + ko, dstB[seg]);
    // A fragment loads (global, coalesced, L2-hit): latency overlaps drain.
    i32x4 af[4];
    #pragma unroll
    for (int t = 0; t < 4; ++t)
      af[t] = *reinterpret_cast<const i32x4*>(agp[t] + kc * 1024);
    __syncthreads();                   // drains DMA -> B tile visible

    i32x4 bf[4];
    #pragma unroll
    for (int u = 0; u < 4; ++u) bf[u] = *reinterpret_cast<const i32x4*>(bfp[u]);
    #pragma unroll
    for (int t = 0; t < 4; ++t)
      #pragma unroll
      for (int u = 0; u < 4; ++u)
        acc[t][u] = __builtin_amdgcn_mfma_i32_16x16x64_i8(
            af[t], bf[u], acc[t][u], 0, 0, 0);
  }

  // Epilogue. C/D layout: col = lane&15, row = quad*4 + reg (m89-verified,
  // dtype-independent on gfx950). sim = i32dot * (s/127)^2 / T.
  float re[4][4];
  float ce[4];
  #pragma unroll
  for (int t = 0; t < 4; ++t)
    #pragma unroll
    for (int r = 0; r < 4; ++r) re[t][r] = 0.0f;
  #pragma unroll
  for (int u = 0; u < 4; ++u) ce[u] = 0.0f;

  #pragma unroll
  for (int t = 0; t < 4; ++t) {
    #pragma unroll
    for (int u = 0; u < 4; ++u) {
      i32x4 a = acc[t][u];
      const int gc = col0 + wc0 + u * 16 + colid;
      #pragma unroll
      for (int r = 0; r < 4; ++r) {
        int grow = row0 + wr0 + t * 16 + quad * 4 + r;
        float sim = (float)a[r] * SIMSCALE;
        float e = (gc > grow) ? __expf(sim) : 0.0f;  // strict upper triangle
        re[t][r] += e;
        ce[u] += e;
        if (gc == grow + HALF_N && grow < HALF_N) {
          pairsim[grow] = sim;         // unique writer per pair
          pairsim[gc] = sim;
        }
      }
    }
  }

  // Row sums: reduce across the 16 col-lanes, LDS-accumulate.
  #pragma unroll
  for (int t = 0; t < 4; ++t)
    #pragma unroll
    for (int r = 0; r < 4; ++r) {
      float v = re[t][r];
      v += __shfl_xor(v, 1); v += __shfl_xor(v, 2);
      v += __shfl_xor(v, 4); v += __shfl_xor(v, 8);
      if (colid == 0) atomicAdd(&redrow[wr0 + t * 16 + quad * 4 + r], v);
    }
  // Col sums: reduce across the 4 quads (this wave's 64 rows).
  #pragma unroll
  for (int u = 0; u < 4; ++u) {
    float v = ce[u];
    v += __shfl_xor(v, 16); v += __shfl_xor(v, 32);
    if (lane < 16) atomicAdd(&redcol[wc0 + u * 16 + colid], v);
  }
  __syncthreads();
  if (tid < 128) atomicAdd(&rowsum[row0 + tid], redrow[tid]);
  else           atomicAdd(&rowsum[col0 + tid - 128], redcol[tid - 128]);
}

// Kernel 3: loss partials. 32 blocks x 256 threads, one row each;
// per-wave reduce then one atomicAdd per wave into out (zeroed in kernel 1).
__global__ __launch_bounds__(256) void finalize_k(
    const float* __restrict__ rowsum, const float* __restrict__ pairsim,
    float* __restrict__ out) {
  int i = blockIdx.x * 256 + threadIdx.x;
  float local = logf(rowsum[i]) - pairsim[i];
  #pragma unroll
  for (int off = 1; off < 64; off <<= 1) local += __shfl_xor(local, off);
  if ((threadIdx.x & 63) == 0)
    atomicAdd(out, local * (1.0f / (float)NROWS));
}

extern "C" void kernel_launch(void* const* d_in, const int* in_sizes, int n_in,
                              void* d_out, int out_size, void* d_ws, size_t ws_size,
                              hipStream_t stream) {
  const float* f1 = (const float*)d_in[0];
  const float* f2 = (const float*)d_in[1];
  unsigned char* Fa = (unsigned char*)d_ws;                     // 4 MB i8
  unsigned char* Fb = Fa + (size_t)NROWS * DIM;                 // 4 MB i8
  float* rowsum = (float*)(Fb + (size_t)NROWS * DIM);
  float* pairsim = rowsum + NROWS;
  float* out = (float*)d_out;

  norm_cast_k<<<NROWS / 4, 256, 0, stream>>>(f1, f2, Fa, Fb, rowsum, out);
  sym_gemm_k<<<NBLOCKS, 256, 0, stream>>>(Fa, Fb, rowsum, pairsim);
  finalize_k<<<NROWS / 256, 256, 0, stream>>>(rowsum, pairsim, out);
}

// Round 16
// 104.769 us; speedup vs baseline: 1.0292x; 1.0217x over previous
//
#include <hip/hip_runtime.h>

#define NROWS 8192
#define HALF_N 4096
#define DIM 512
#define INV_T 10.0f
#define NRB 64              // number of 128-row blocks
#define NBLOCKS 2080        // 64*65/2 upper-triangle block pairs

typedef __attribute__((ext_vector_type(4))) float f32x4;
typedef __attribute__((ext_vector_type(2))) long long2v;

// async 16B global -> LDS (DMA). LDS dest is wave-uniform base + lane*16.
__device__ __forceinline__ void async16(const void* g, void* l) {
  __builtin_amdgcn_global_load_lds(
      (const __attribute__((address_space(1))) unsigned int*)g,
      (__attribute__((address_space(3))) unsigned int*)l, 16, 0, 0);
}

// Kernel 1: L2-normalize rows of [f1;f2] -> fp8 e4m3, written TWICE:
//  Fb: row-major, k-permuted within each 64B group (unit u -> pos
//      2*(u&3)+(u>>2)) — the B/LDS copy (R8-proven geometry).
//  Fa: fragment-major — panel p = row>>4 is 8 KB laid out as
//      [chunk c=0..31][row&15][16B], where chunk c holds k-units {c&3, (c&3)+4}
//      of k-group c>>2 (same pairing as Fb). A-fragment loads in the GEMM
//      become coalesced global b128 (quarter-wave = 256 B contiguous).
__global__ __launch_bounds__(256) void norm_cast_k(
    const float* __restrict__ f1, const float* __restrict__ f2,
    unsigned char* __restrict__ Fa, unsigned char* __restrict__ Fb,
    float* __restrict__ rowsum, float* __restrict__ out) {
  int wave = threadIdx.x >> 6;
  int lane = threadIdx.x & 63;
  int row = blockIdx.x * 4 + wave;
  const float* src = (row < HALF_N) ? (f1 + (size_t)row * DIM)
                                    : (f2 + (size_t)(row - HALF_N) * DIM);
  const float4* p = reinterpret_cast<const float4*>(src + lane * 8);
  float4 v0 = p[0];
  float4 v1 = p[1];
  float ss = v0.x*v0.x + v0.y*v0.y + v0.z*v0.z + v0.w*v0.w
           + v1.x*v1.x + v1.y*v1.y + v1.z*v1.z + v1.w*v1.w;
  #pragma unroll
  for (int off = 1; off < 64; off <<= 1) ss += __shfl_xor(ss, off);
  float scale = 1.0f / fmaxf(sqrtf(ss), 1e-12f);
  int lo = __builtin_amdgcn_cvt_pk_fp8_f32(v0.x * scale, v0.y * scale, 0, false);
  lo = __builtin_amdgcn_cvt_pk_fp8_f32(v0.z * scale, v0.w * scale, lo, true);
  int hi = __builtin_amdgcn_cvt_pk_fp8_f32(v1.x * scale, v1.y * scale, 0, false);
  hi = __builtin_amdgcn_cvt_pk_fp8_f32(v1.z * scale, v1.w * scale, hi, true);
  int2 val = make_int2(lo, hi);
  int u = lane & 7;                     // k-unit within 64B group
  int g = lane >> 3;                    // k-group (0..7)
  // Fb: row-major k-permuted
  int pos = 2 * (u & 3) + (u >> 2);
  *reinterpret_cast<int2*>(Fb + (size_t)row * DIM + g * 64 + pos * 8) = val;
  // Fa: fragment-major
  int chunk = g * 4 + (u & 3);          // global 16B chunk index (0..31)
  int slot = u >> 2;                    // which 8B half of the chunk
  *reinterpret_cast<int2*>(Fa + (size_t)(row >> 4) * 8192 + chunk * 256 +
                           (row & 15) * 16 + slot * 8) = val;
  if (lane == 0) rowsum[row] = 0.0f;
  if (blockIdx.x == 0 && threadIdx.x == 0) out[0] = 0.0f;
}

// Kernel 2: symmetric upper-triangle sim GEMM (fp8 e4m3), fused exp row/col
// accumulation. 128x128 tiles, BK=64 (8 rounds). B staged via global_load_lds
// (8 x 1KB insts/round, R8-proven swizzle); A fragments loaded DIRECTLY from
// global (Fa fragment-major copy, coalesced b128, L2-resident) — decoupled
// from the LDS barrier so their latency overlaps the DMA drain.
// [Session best: ~40 µs GEMM / ~103.7 µs total. Structural plateau: six
// orthogonal K-loop restructurings (dbuf, barrier/2, occ+1, DS/2,
// barrier-free, i8 K=64) all land 40-50 µs — per-wave load->MFMA latency,
// beyond HIP source-level scheduling control.]
__global__ __launch_bounds__(256, 3) void sym_gemm_k(
    const unsigned char* __restrict__ Fa, const unsigned char* __restrict__ Fb,
    float* __restrict__ rowsum, float* __restrict__ pairsim) {
  // XCD-contiguous remap: each XCD (bx%8) gets a contiguous 260-block range
  int bx = blockIdx.x;
  int gbx = (bx & 7) * (NBLOCKS / 8) + (bx >> 3);
  int rb = 0, rem = gbx;
  while (rem >= NRB - rb) { rem -= NRB - rb; ++rb; }
  const int cb = rb + rem;
  const int row0 = rb * 128, col0 = cb * 128;

  const int tid = threadIdx.x;
  const int wave = tid >> 6;
  const int lane = tid & 63;
  const int quad = lane >> 4;
  const int colid = lane & 15;
  const int wr0 = (wave >> 1) * 64;   // wave's row offset within tile
  const int wc0 = (wave & 1) * 64;    // wave's col offset within tile

  // B LDS tile: 128 rows x 64 k fp8 = 64 B/row, 4 x 16B chunks per row.
  // Physical chunk = logical ^ ((row>>1)&3) -> conflict-free b128 reads.
  __shared__ __align__(16) unsigned char Blds[128 * 64];
  __shared__ float redrow[128];
  __shared__ float redcol[128];

  if (tid < 128) { redrow[tid] = 0.0f; redcol[tid] = 0.0f; }

  // B staging: 8 x 1KB insts/round, wave w owns insts {w, w+4}.
  // Inst i covers rows [i*16, i*16+16): lane -> r = i*16 + (lane>>2),
  // phys chunk = lane&3, global logical chunk = (lane&3) ^ ((r>>1)&3).
  const unsigned char* srcB[2]; unsigned char* dstB[2];
  #pragma unroll
  for (int seg = 0; seg < 2; ++seg) {
    int inst = wave + seg * 4;
    int r = inst * 16 + (lane >> 2);
    int c = (lane & 3) ^ ((r >> 1) & 3);
    srcB[seg] = Fb + (size_t)(col0 + r) * DIM + c * 16;
    dstB[seg] = Blds + inst * 1024;   // 16 rows x 64 B per inst
  }

  // A global fragment pointers: tile t -> panel (row0+wr0+t*16)>>4;
  // round kc, quad q -> chunk kc*4+q; lane colid -> row-in-panel.
  // Quarter-wave reads 16 x 16B = 256 B contiguous (coalesced, L2-hit).
  const unsigned char* agp[4];
  #pragma unroll
  for (int t = 0; t < 4; ++t)
    agp[t] = Fa + (size_t)((row0 + wr0 + t * 16) >> 4) * 8192 +
             quad * 256 + colid * 16;

  // B fragment LDS addresses: logical chunk = quad; phys = quad ^ ((r>>1)&3).
  const unsigned char* bfp[4];
  #pragma unroll
  for (int t = 0; t < 4; ++t) {
    int rc = wc0 + t * 16 + colid;
    bfp[t] = Blds + rc * 64 + ((quad ^ ((rc >> 1) & 3)) << 4);
  }

  f32x4 acc[4][4];
  #pragma unroll
  for (int t = 0; t < 4; ++t)
    #pragma unroll
    for (int u = 0; u < 4; ++u) acc[t][u] = (f32x4){0.f, 0.f, 0.f, 0.f};

  for (int kc = 0; kc < 8; ++kc) {
    __syncthreads();                   // prior round's B reads done
    const size_t ko = (size_t)kc * 64; // B: 64 k-elems = 64 B per row
    #pragma unroll
    for (int seg = 0; seg < 2; ++seg)
      async16(srcB[seg] + ko, dstB[seg]);
    // A fragment loads (global, coalesced): issued here so their L2
    // latency overlaps the DMA drain below.
    long2v af[4];
    #pragma unroll
    for (int t = 0; t < 4; ++t)
      af[t] = *reinterpret_cast<const long2v*>(agp[t] + kc * 1024);
    __syncthreads();                   // drains DMA -> B tile visible

    long2v bf[4];
    #pragma unroll
    for (int u = 0; u < 4; ++u) bf[u] = *reinterpret_cast<const long2v*>(bfp[u]);
    #pragma unroll
    for (int s = 0; s < 2; ++s)
      #pragma unroll
      for (int t = 0; t < 4; ++t)
        #pragma unroll
        for (int u = 0; u < 4; ++u)
          acc[t][u] = __builtin_amdgcn_mfma_f32_16x16x32_fp8_fp8(
              af[t][s], bf[u][s], acc[t][u], 0, 0, 0);
  }

  // Epilogue. C/D layout: col = lane&15, row = quad*4 + reg (m89-verified,
  // dtype-independent on gfx950).
  float re[4][4];
  float ce[4];
  #pragma unroll
  for (int t = 0; t < 4; ++t)
    #pragma unroll
    for (int r = 0; r < 4; ++r) re[t][r] = 0.0f;
  #pragma unroll
  for (int u = 0; u < 4; ++u) ce[u] = 0.0f;

  #pragma unroll
  for (int t = 0; t < 4; ++t) {
    #pragma unroll
    for (int u = 0; u < 4; ++u) {
      f32x4 a = acc[t][u];
      const int gc = col0 + wc0 + u * 16 + colid;
      #pragma unroll
      for (int r = 0; r < 4; ++r) {
        int grow = row0 + wr0 + t * 16 + quad * 4 + r;
        float sim = a[r] * INV_T;
        float e = (gc > grow) ? __expf(sim) : 0.0f;  // strict upper triangle
        re[t][r] += e;
        ce[u] += e;
        if (gc == grow + HALF_N && grow < HALF_N) {
          pairsim[grow] = sim;         // unique writer per pair
          pairsim[gc] = sim;
        }
      }
    }
  }

  // Row sums: reduce across the 16 col-lanes, LDS-accumulate.
  #pragma unroll
  for (int t = 0; t < 4; ++t)
    #pragma unroll
    for (int r = 0; r < 4; ++r) {
      float v = re[t][r];
      v += __shfl_xor(v, 1); v += __shfl_xor(v, 2);
      v += __shfl_xor(v, 4); v += __shfl_xor(v, 8);
      if (colid == 0) atomicAdd(&redrow[wr0 + t * 16 + quad * 4 + r], v);
    }
  // Col sums: reduce across the 4 quads (this wave's 64 rows).
  #pragma unroll
  for (int u = 0; u < 4; ++u) {
    float v = ce[u];
    v += __shfl_xor(v, 16); v += __shfl_xor(v, 32);
    if (lane < 16) atomicAdd(&redcol[wc0 + u * 16 + colid], v);
  }
  __syncthreads();
  if (tid < 128) atomicAdd(&rowsum[row0 + tid], redrow[tid]);
  else           atomicAdd(&rowsum[col0 + tid - 128], redcol[tid - 128]);
}

// Kernel 3: loss partials. 32 blocks x 256 threads, one row each;
// per-wave reduce then one atomicAdd per wave into out (zeroed in kernel 1).
__global__ __launch_bounds__(256) void finalize_k(
    const float* __restrict__ rowsum, const float* __restrict__ pairsim,
    float* __restrict__ out) {
  int i = blockIdx.x * 256 + threadIdx.x;
  float local = logf(rowsum[i]) - pairsim[i];
  #pragma unroll
  for (int off = 1; off < 64; off <<= 1) local += __shfl_xor(local, off);
  if ((threadIdx.x & 63) == 0)
    atomicAdd(out, local * (1.0f / (float)NROWS));
}

extern "C" void kernel_launch(void* const* d_in, const int* in_sizes, int n_in,
                              void* d_out, int out_size, void* d_ws, size_t ws_size,
                              hipStream_t stream) {
  const float* f1 = (const float*)d_in[0];
  const float* f2 = (const float*)d_in[1];
  unsigned char* Fa = (unsigned char*)d_ws;                     // 4 MB fp8
  unsigned char* Fb = Fa + (size_t)NROWS * DIM;                 // 4 MB fp8
  float* rowsum = (float*)(Fb + (size_t)NROWS * DIM);
  float* pairsim = rowsum + NROWS;
  float* out = (float*)d_out;

  norm_cast_k<<<NROWS / 4, 256, 0, stream>>>(f1, f2, Fa, Fb, rowsum, out);
  sym_gemm_k<<<NBLOCKS, 256, 0, stream>>>(Fa, Fb, rowsum, pairsim);
  finalize_k<<<NROWS / 256, 256, 0, stream>>>(rowsum, pairsim, out);
}